// Round 15
// baseline (709.160 us; speedup 1.0000x reference)
//
#include <hip/hip_runtime.h>
#include <hip/hip_bf16.h>

typedef unsigned int u32;
typedef unsigned short u16;
typedef __attribute__((ext_vector_type(8))) short short8;   // 8 bf16 (4 VGPRs)
typedef __attribute__((ext_vector_type(4))) float f32x4;    // MFMA C/D
typedef __attribute__((ext_vector_type(2))) float f32x2;    // v_pk_fma_f32 operand
typedef __attribute__((ext_vector_type(4))) u32 u32x4;

#define N_PTS 100000
#define NSAMP 16

__device__ __forceinline__ float lo2f(u32 u){ return __uint_as_float(u << 16); }
__device__ __forceinline__ float hi2f(u32 u){ return __uint_as_float(u & 0xffff0000u); }
__device__ __forceinline__ float us2f(u16 u){ return __uint_as_float(((u32)u) << 16); }

// round-to-nearest-even f32 -> bf16 bits (finite values only)
__device__ __forceinline__ u16 f2bf(float f) {
    u32 u = __float_as_uint(f);
    return (u16)((u + 0x7fffu + ((u >> 16) & 1u)) >> 16);
}
__device__ __forceinline__ u32 pack2(float k, float v) {
    return (u32)f2bf(k) | ((u32)f2bf(v) << 16);
}

// wave-local LDS RAW fence. The "memory" clobber ALSO pins global loads
// above it (they cannot sink past) — R4/R11-proven mechanism that keeps
// the whole gather burst issued up-front.
#define WAVE_LDS_FENCE() asm volatile("s_waitcnt lgkmcnt(0)" ::: "memory")

// Runtime input-dtype probe (must be called by ALL threads of the block).
__device__ __forceinline__ bool detect_f32(const u16* __restrict__ xprobe) {
    float f = us2f(xprobe[(threadIdx.x & 63) * 2]);
    int cnt = __syncthreads_count(fabsf(f) > 1024.0f ? 1 : 0);
    return cnt >= 8;
}

// generic raw-weight element load (fp32 or bf16 source)
__device__ __forceinline__ float rawf(const void* s, int i, bool isf32) {
    return isf32 ? ((const float*)s)[i] : us2f(((const u16*)s)[i]);
}

// canonical fp32 weight-block offsets (floats) — written by qkv block 0,
// consumed by attn (stream-ordered).
#define OFF_WP1  0
#define OFF_BP1  12
#define OFF_GP   16
#define OFF_BP   20
#define OFF_WP2  24
#define OFF_BP2  216
#define OFF_G1   280
#define OFF_BB1  344
#define OFF_BA   408
#define OFF_G2   416
#define OFF_BB2  424
#define OFF_BW   432
#define OFF_WAT  448     /* WaT[s][c] : 8 x 64 f32 (transposed Wa) */
#define OFF_WBT  960     /* WbT[t][s] : 8 x 8  f32 (transposed Wb) */
#define CW_PAD   4096    /* pad to 16 KB of floats */

// ---------------------------------------------------------------------------
// K1: MFMA QKV projection + (block 0) attn-weight canonicalization.
// (round-13 version: swapped operands + vectorized float4/uint4 epilogue —
// passing; non-attn residual proved insensitive to qkv shape, so frozen.)
// ---------------------------------------------------------------------------
#define QKV_TPB 10
__global__ __launch_bounds__(256) void qkv_mfma_kernel(
    const u16* __restrict__ xraw,
    const void* s0,  const void* s1,  const void* s2,  const void* s3,
    const void* s4,  const void* s5,  const void* s6,  const void* s7,
    const void* s8,  const void* s9,  const void* s10, const void* s11,
    const void* s12, const void* s13, const void* s14, const void* s15,
    const void* s16, const void* s17, const void* s18, const void* s19,
    float* __restrict__ cw,
    float* __restrict__ Q, u32* __restrict__ KV)
{
    bool isf32 = detect_f32(xraw);
    const int w   = threadIdx.x >> 6;
    const int l   = threadIdx.x & 63;
    const int col = l & 15;
    const int g   = l >> 4;

    // ---- block 0: write attn's canonical weight block ----
    if (blockIdx.x == 0) {
        const void* srcs[12] = {s6,s7,s8,s9,s10,s11,s12,s13,s15,s16,s17,s19};
        const int   sizes[12]= {9,3,3,3,192,64,64,64,8,8,8,8};
        const int   offs[12] = {OFF_WP1,OFF_BP1,OFF_GP,OFF_BP,OFF_WP2,OFF_BP2,
                                OFF_G1,OFF_BB1,OFF_BA,OFF_G2,OFF_BB2,OFF_BW};
        int tid = threadIdx.x;
        for (int a = 0; a < 12; a++)
            for (int k = tid; k < sizes[a]; k += 256)
                cw[offs[a] + k] = rawf(srcs[a], k, isf32);
        // WaT[s][c] = Wa[c][s] ; WbT[t][s] = Wb[s][t]
        for (int t = tid; t < 512 + 64; t += 256) {
            if (t < 512) {
                int s = t >> 6, cc = t & 63;
                cw[OFF_WAT + s * 64 + cc] = rawf(s14, cc * 8 + s, isf32);
            } else {
                int r = t - 512;
                int tt = r >> 3, ss = r & 7;
                cw[OFF_WBT + tt * 8 + ss] = rawf(s18, ss * 8 + tt, isf32);
            }
        }
    }

    // ---- build W fragments in registers: hi/lo bf16 planes ----
    const void* wsrc[3] = {s0, s2, s4};
    short8 bh[3][2], bl[3][2];
#pragma unroll
    for (int m = 0; m < 3; m++)
#pragma unroll
        for (int kh = 0; kh < 2; kh++)
#pragma unroll
            for (int j = 0; j < 8; j++) {
                float wv_ = rawf(wsrc[m], (kh * 32 + g * 8 + j) * 64 + w * 16 + col, isf32);
                u16 hb = f2bf(wv_);
                bh[m][kh][j] = (short)hb;
                bl[m][kh][j] = (short)f2bf(wv_ - us2f(hb));
            }
    // per-reg bias (D row m = g*4+r -> weight col w*16+g*4+r), loop-invariant
    float bq[4], bk[4], bv[4];
#pragma unroll
    for (int r = 0; r < 4; r++) {
        bq[r] = rawf(s1, w * 16 + g * 4 + r, isf32);
        bk[r] = rawf(s3, w * 16 + g * 4 + r, isf32);
        bv[r] = rawf(s5, w * 16 + g * 4 + r, isf32);
    }

#define LOAD_A(IT, AH, AL)                                                        \
    {                                                                             \
        const int M0_ = (blockIdx.x * QKV_TPB + (IT)) * 16;                       \
        if (isf32) {                                                              \
            const float4* xf = (const float4*)xraw;                               \
            _Pragma("unroll")                                                     \
            for (int kh = 0; kh < 2; kh++) {                                      \
                float4 f0 = xf[(size_t)(M0_ + col) * 16 + kh * 8 + g * 2];        \
                float4 f1 = xf[(size_t)(M0_ + col) * 16 + kh * 8 + g * 2 + 1];    \
                float ff[8] = {f0.x, f0.y, f0.z, f0.w, f1.x, f1.y, f1.z, f1.w};   \
                _Pragma("unroll")                                                 \
                for (int j = 0; j < 8; j++) {                                     \
                    u16 hb_ = f2bf(ff[j]);                                        \
                    AH[kh][j] = (short)hb_;                                       \
                    AL[kh][j] = (short)f2bf(ff[j] - us2f(hb_));                   \
                }                                                                 \
            }                                                                     \
        } else {                                                                  \
            const short8* xb = (const short8*)xraw;                               \
            _Pragma("unroll")                                                     \
            for (int kh = 0; kh < 2; kh++)                                        \
                AH[kh] = xb[(size_t)(M0_ + col) * 8 + kh * 4 + g];                \
        }                                                                         \
    }

    short8 ahA[2], alA[2], ahB[2], alB[2];
    LOAD_A(0, ahA, alA);

#pragma unroll
    for (int it = 0; it < QKV_TPB; it++) {
        short8 (&ah)[2] = (it & 1) ? ahB : ahA;
        short8 (&al)[2] = (it & 1) ? alB : alA;
        short8 (&ahN)[2] = (it & 1) ? ahA : ahB;
        short8 (&alN)[2] = (it & 1) ? alA : alB;
        if (it + 1 < QKV_TPB) LOAD_A(it + 1, ahN, alN);

        const int M0 = (blockIdx.x * QKV_TPB + it) * 16;
        f32x4 aQ = {bq[0], bq[1], bq[2], bq[3]};
        f32x4 aK = {bk[0], bk[1], bk[2], bk[3]};
        f32x4 aV = {bv[0], bv[1], bv[2], bv[3]};

        // SWAPPED operand order: D = Wfrag . xfrag  -> D[m=W col][n=x row]
#pragma unroll
        for (int kh = 0; kh < 2; kh++) {
            aQ = __builtin_amdgcn_mfma_f32_16x16x32_bf16(bh[0][kh], ah[kh], aQ, 0, 0, 0);
            aK = __builtin_amdgcn_mfma_f32_16x16x32_bf16(bh[1][kh], ah[kh], aK, 0, 0, 0);
            aV = __builtin_amdgcn_mfma_f32_16x16x32_bf16(bh[2][kh], ah[kh], aV, 0, 0, 0);
            aQ = __builtin_amdgcn_mfma_f32_16x16x32_bf16(bl[0][kh], ah[kh], aQ, 0, 0, 0);
            aK = __builtin_amdgcn_mfma_f32_16x16x32_bf16(bl[1][kh], ah[kh], aK, 0, 0, 0);
            aV = __builtin_amdgcn_mfma_f32_16x16x32_bf16(bl[2][kh], ah[kh], aV, 0, 0, 0);
            if (isf32) {
                aQ = __builtin_amdgcn_mfma_f32_16x16x32_bf16(bh[0][kh], al[kh], aQ, 0, 0, 0);
                aK = __builtin_amdgcn_mfma_f32_16x16x32_bf16(bh[1][kh], al[kh], aK, 0, 0, 0);
                aV = __builtin_amdgcn_mfma_f32_16x16x32_bf16(bh[2][kh], al[kh], aV, 0, 0, 0);
            }
        }

        // ---- vectorized epilogue: lane owns row M0+(l&15), cols w*16+g*4.. ----
        {
            const int row = M0 + col;                 // col == l&15
            float4 qv = {aQ[0], aQ[1], aQ[2], aQ[3]};
            *(float4*)&Q[(size_t)row * 64 + w * 16 + g * 4] = qv;
            u32x4 kvv = {pack2(aK[0], aV[0]), pack2(aK[1], aV[1]),
                         pack2(aK[2], aV[2]), pack2(aK[3], aV[3])};
            *(u32x4*)&KV[(size_t)row * 64 + w * 16 + g * 4] = kvv;
        }
    }
#undef LOAD_A
}

// ---------------------------------------------------------------------------
// K2: fused attention — round 15 = round 14 with PHASED wvbuf:
// each wave owns ONE wvbuf slice and runs {stage1, stage2} twice (pt0 then
// pt1). The 32-gather pinned burst is untouched; only consumption order
// changes (bit-identical per-element math). LDS 38.9 -> 21.5 KB:
//   wvbuf[4][16*68] (per-wave, phased; also w2 overlay after stage 2)
//   tbbuf[8][16*8]  (per-point;   [0..63] reused as hbuf pre-stage1)
// __launch_bounds__(256,6) -> 6 blocks/CU = 24 waves/CU (R14: 16).
// ---------------------------------------------------------------------------
__global__ __launch_bounds__(256, 6) void attn_kernel(
    const u16* __restrict__ P, const int* __restrict__ IDX,
    const u16* __restrict__ xprobe, const float* __restrict__ cw,
    const float* __restrict__ Q, const u32* __restrict__ KV,
    void* __restrict__ OUT)
{
    __shared__ __align__(16) float wvbuf[4][NSAMP * 68];  // per-WAVE, phased
    __shared__ __align__(16) float tbbuf[8][NSAMP * 8];   // per-point

    bool isf32 = detect_f32(xprobe);

    const int pt  = threadIdx.x >> 6;
    const int c   = threadIdx.x & 63;
    const int i0  = blockIdx.x * 8 + pt * 2;   // grid*8 == N_PTS exactly
    const int i1  = i0 + 1;
    const int sl0 = pt * 2, sl1 = sl0 + 1;     // wave-owned tbbuf slices
    const float rs = 1.0f / sqrtf(1.0f + 1e-5f);

    // lifetime-overlay views (all wave-owned)
    float* hb0 = &tbbuf[sl0][0];        // hbuf pt0 (64 floats, dead after st1-A)
    float* hb1 = &tbbuf[sl1][0];        // hbuf pt1 (dead after st1-B)
    float* w20 = &wvbuf[pt][0];         // softmax weights pt0 (128 floats)
    float* w21 = &wvbuf[pt][128];       // softmax weights pt1

    // ---- burst: indices + 32 KV gathers + Q + P, all before the fence ----
    const int jv0 = IDX[(size_t)i0 * NSAMP + (c & 15)];
    const int jv1 = IDX[(size_t)i1 * NSAMP + (c & 15)];

    u32 kv0[NSAMP], kv1[NSAMP];
    const u32* KVc = KV + c;
#pragma unroll
    for (int n = 0; n < NSAMP; n++) {
        int j = __builtin_amdgcn_readlane(jv0, n);   // SGPR -> SALU addressing
        kv0[n] = KVc[(size_t)j << 6];
    }
#pragma unroll
    for (int n = 0; n < NSAMP; n++) {
        int j = __builtin_amdgcn_readlane(jv1, n);
        kv1[n] = KVc[(size_t)j << 6];
    }

    const float qq0 = Q[(size_t)i0 * 64 + c];
    const float qq1 = Q[(size_t)i1 * 64 + c];

    // ---- distributed h-MLP for both points: lane (n,d) = (c/3, c%3) ----
    const float* Pf = (const float*)P;
    const int n_p  = c / 3;
    const int d_p  = c - n_p * 3;
    const int np15 = n_p & 15;
    const int jp0  = __shfl(jv0, np15, 64);
    const int jp1  = __shfl(jv1, np15, 64);
    float pj0, pj1, pid0, pid1;
    if (isf32) {
        pj0 = Pf[(size_t)jp0 * 3 + d_p];  pid0 = Pf[(size_t)i0 * 3 + d_p];
        pj1 = Pf[(size_t)jp1 * 3 + d_p];  pid1 = Pf[(size_t)i1 * 3 + d_p];
    } else {
        pj0 = us2f(P[(size_t)jp0 * 3 + d_p]);  pid0 = us2f(P[(size_t)i0 * 3 + d_p]);
        pj1 = us2f(P[(size_t)jp1 * 3 + d_p]);  pid1 = us2f(P[(size_t)i1 * 3 + d_p]);
    }
    const float pr0 = pj0 - pid0, pr1 = pj1 - pid1;
    const int lb = np15 * 3;
    const float pA0 = __shfl(pr0, lb + 0, 64);
    const float pA1 = __shfl(pr0, lb + 1, 64);
    const float pA2 = __shfl(pr0, lb + 2, 64);
    const float pB0 = __shfl(pr1, lb + 0, 64);
    const float pB1 = __shfl(pr1, lb + 1, 64);
    const float pB2 = __shfl(pr1, lb + 2, 64);
    {
        float gd  = cw[OFF_GP + d_p] * rs;
        float w0s = cw[OFF_WP1 + 0 * 3 + d_p] * gd;
        float w1s = cw[OFF_WP1 + 1 * 3 + d_p] * gd;
        float w2s = cw[OFF_WP1 + 2 * 3 + d_p] * gd;
        float bs  = cw[OFF_BP1 + d_p] * gd + cw[OFF_BP + d_p];
        float hA = fmaxf(fmaf(pA2, w2s, fmaf(pA1, w1s, fmaf(pA0, w0s, bs))), 0.0f);
        float hB = fmaxf(fmaf(pB2, w2s, fmaf(pB1, w1s, fmaf(pB0, w0s, bs))), 0.0f);
        if (c < 48) {
            hb0[np15 * 4 + d_p] = hA;
            hb1[np15 * 4 + d_p] = hB;
        }
    }
    WAVE_LDS_FENCE();   // hbuf RAW (same wave) + pins the 32 gathers above

    // per-lane channel constants (L1-hot)
    const float wp2c0 = cw[OFF_WP2 + 0 * 64 + c];
    const float wp2c1 = cw[OFF_WP2 + 1 * 64 + c];
    const float wp2c2 = cw[OFF_WP2 + 2 * 64 + c];
    const float bp2c  = cw[OFF_BP2 + c];
    const float g1c   = cw[OFF_G1  + c] * rs;
    const float bb1c  = cw[OFF_BB1 + c];
    const int s2s = c & 7, s2n = c >> 3;
    const float4* waT4 = (const float4*)(cw + OFF_WAT + s2s * 64);
    const float ba_s  = cw[OFF_BA + s2s];
    const float g2s   = cw[OFF_G2 + s2s] * rs;
    const float bb2s  = cw[OFF_BB2 + s2s];

    float pv0[NSAMP], pv1[NSAMP];

    // =================== PHASE A: stage1 + stage2 for point 0 ==============
#pragma unroll
    for (int n = 0; n < NSAMP; n++) {
        float4 hb = *((const float4*)&hb0[n * 4]);
        float pe = fmaf(hb.z, wp2c2, fmaf(hb.y, wp2c1, fmaf(hb.x, wp2c0, bp2c)));
        float kk = lo2f(kv0[n]);
        float vv = hi2f(kv0[n]);
        wvbuf[pt][n * 68 + c] = fmaxf(fmaf(kk - qq0 + pe, g1c, bb1c), 0.0f);
        pv0[n] = vv + pe;
    }
    __syncthreads();

    {   // stage 2 (pt0): merged reps, f32x2 packed -> tbbuf[sl0]
        f32x2 a0v = {ba_s, 0.0f};
        f32x2 a1v = a0v;
#pragma unroll
        for (int c4 = 0; c4 < 16; c4++) {
            float4 wa  = waT4[c4];
            float4 w40 = *((const float4*)&wvbuf[pt][s2n * 68 + c4 * 4]);
            float4 w41 = *((const float4*)&wvbuf[pt][(s2n + 8) * 68 + c4 * 4]);
            f32x2 waA = {wa.x, wa.y},  waB = {wa.z, wa.w};
            f32x2 p0A = {w40.x, w40.y}, p0B = {w40.z, w40.w};
            f32x2 p1A = {w41.x, w41.y}, p1B = {w41.z, w41.w};
            a0v += p0A * waA;  a0v += p0B * waB;
            a1v += p1A * waA;  a1v += p1B * waB;
        }
        tbbuf[sl0][s2n * 8 + s2s]       = fmaxf(fmaf(a0v.x + a0v.y, g2s, bb2s), 0.0f);
        tbbuf[sl0][(s2n + 8) * 8 + s2s] = fmaxf(fmaf(a1v.x + a1v.y, g2s, bb2s), 0.0f);
    }
    __syncthreads();

    // =================== PHASE B: stage1 + stage2 for point 1 ==============
#pragma unroll
    for (int n = 0; n < NSAMP; n++) {
        float4 hb = *((const float4*)&hb1[n * 4]);
        float pe = fmaf(hb.z, wp2c2, fmaf(hb.y, wp2c1, fmaf(hb.x, wp2c0, bp2c)));
        float kk = lo2f(kv1[n]);
        float vv = hi2f(kv1[n]);
        wvbuf[pt][n * 68 + c] = fmaxf(fmaf(kk - qq1 + pe, g1c, bb1c), 0.0f);
        pv1[n] = vv + pe;
    }
    __syncthreads();

    {   // stage 2 (pt1) -> tbbuf[sl1]
        f32x2 a0v = {ba_s, 0.0f};
        f32x2 a1v = a0v;
#pragma unroll
        for (int c4 = 0; c4 < 16; c4++) {
            float4 wa  = waT4[c4];
            float4 w40 = *((const float4*)&wvbuf[pt][s2n * 68 + c4 * 4]);
            float4 w41 = *((const float4*)&wvbuf[pt][(s2n + 8) * 68 + c4 * 4]);
            f32x2 waA = {wa.x, wa.y},  waB = {wa.z, wa.w};
            f32x2 p0A = {w40.x, w40.y}, p0B = {w40.z, w40.w};
            f32x2 p1A = {w41.x, w41.y}, p1B = {w41.z, w41.w};
            a0v += p0A * waA;  a0v += p0B * waB;
            a1v += p1A * waA;  a1v += p1B * waB;
        }
        tbbuf[sl1][s2n * 8 + s2s]       = fmaxf(fmaf(a0v.x + a0v.y, g2s, bb2s), 0.0f);
        tbbuf[sl1][(s2n + 8) * 8 + s2s] = fmaxf(fmaf(a1v.x + a1v.y, g2s, bb2s), 0.0f);
    }
    __syncthreads();

    // ---- stage 3 (both points): logits in registers ----
    f32x2 wA0 = {cw[OFF_BW + s2s], 0.0f};
    f32x2 wA1 = wA0, wB0 = wA0, wB1 = wA0;
    {
        float4 wb0 = *(const float4*)(cw + OFF_WBT + s2s * 8);
        float4 wb1 = *(const float4*)(cw + OFF_WBT + s2s * 8 + 4);
        f32x2 b0 = {wb0.x, wb0.y}, b1 = {wb0.z, wb0.w};
        f32x2 b2 = {wb1.x, wb1.y}, b3 = {wb1.z, wb1.w};
#define ACC_LOGIT(ACC, SL, ROW)                                                   \
        {                                                                         \
            float4 t0_ = *((const float4*)&tbbuf[SL][(ROW) * 8]);                 \
            float4 t1_ = *((const float4*)&tbbuf[SL][(ROW) * 8 + 4]);             \
            f32x2 u0_ = {t0_.x, t0_.y}, u1_ = {t0_.z, t0_.w};                     \
            f32x2 u2_ = {t1_.x, t1_.y}, u3_ = {t1_.z, t1_.w};                     \
            ACC += u0_ * b0;  ACC += u1_ * b1;  ACC += u2_ * b2;  ACC += u3_ * b3;\
        }
        ACC_LOGIT(wA0, sl0, s2n)
        ACC_LOGIT(wA1, sl0, s2n + 8)
        ACC_LOGIT(wB0, sl1, s2n)
        ACC_LOGIT(wB1, sl1, s2n + 8)
#undef ACC_LOGIT
    }
    float lA0 = wA0.x + wA0.y, lA1 = wA1.x + wA1.y;
    float lB0 = wB0.x + wB0.y, lB1 = wB1.x + wB1.y;

    // ---- stage 4: softmax per point over n; weights into w2 overlay ----
    {
        float m0 = fmaxf(lA0, lA1);
        m0 = fmaxf(m0, __shfl_xor(m0, 8, 64));
        m0 = fmaxf(m0, __shfl_xor(m0, 16, 64));
        m0 = fmaxf(m0, __shfl_xor(m0, 32, 64));
        float e00 = __expf(lA0 - m0), e01 = __expf(lA1 - m0);
        float s0 = e00 + e01;
        s0 += __shfl_xor(s0, 8, 64);
        s0 += __shfl_xor(s0, 16, 64);
        s0 += __shfl_xor(s0, 32, 64);
        float inv0 = 1.0f / s0;
        w20[s2n * 8 + s2s]       = e00 * inv0;
        w20[(s2n + 8) * 8 + s2s] = e01 * inv0;

        float m1 = fmaxf(lB0, lB1);
        m1 = fmaxf(m1, __shfl_xor(m1, 8, 64));
        m1 = fmaxf(m1, __shfl_xor(m1, 16, 64));
        m1 = fmaxf(m1, __shfl_xor(m1, 32, 64));
        float e10 = __expf(lB0 - m1), e11 = __expf(lB1 - m1);
        float s1 = e10 + e11;
        s1 += __shfl_xor(s1, 8, 64);
        s1 += __shfl_xor(s1, 16, 64);
        s1 += __shfl_xor(s1, 32, 64);
        float inv1 = 1.0f / s1;
        w21[s2n * 8 + s2s]       = e10 * inv1;
        w21[(s2n + 8) * 8 + s2s] = e11 * inv1;
    }
    __syncthreads();

    // ---- stage 5 (both points): out[c] = sum_n pv[n] * w[n][c&7] ----
    f32x2 ov0 = {0.0f, 0.0f}, ov1 = {0.0f, 0.0f};
#pragma unroll
    for (int n = 0; n < NSAMP; n += 2) {
        f32x2 p0 = {pv0[n], pv0[n + 1]};
        f32x2 w0 = {w20[n * 8 + s2s], w20[(n + 1) * 8 + s2s]};
        f32x2 p1 = {pv1[n], pv1[n + 1]};
        f32x2 w1 = {w21[n * 8 + s2s], w21[(n + 1) * 8 + s2s]};
        ov0 += p0 * w0;
        ov1 += p1 * w1;
    }
    float o0 = ov0.x + ov0.y;
    float o1 = ov1.x + ov1.y;
    if (isf32) {
        ((float*)OUT)[(size_t)i0 * 64 + c] = o0;
        ((float*)OUT)[(size_t)i1 * 64 + c] = o1;
    } else {
        ((__hip_bfloat16*)OUT)[(size_t)i0 * 64 + c] = __float2bfloat16(o0);
        ((__hip_bfloat16*)OUT)[(size_t)i1 * 64 + c] = __float2bfloat16(o1);
    }
}

// ---------------------------------------------------------------------------
extern "C" void kernel_launch(void* const* d_in, const int* in_sizes, int n_in,
                              void* d_out, int out_size, void* d_ws, size_t ws_size,
                              hipStream_t stream)
{
    const u16* p   = (const u16*)d_in[0];
    const u16* x   = (const u16*)d_in[1];
    const int* idx = (const int*)d_in[2];

    // workspace layout: cw 16KB + Q 25.6MB + KV 25.6MB ≈ 51.2 MB
    float* cw = (float*)d_ws;                   // 16 KB
    float* Q  = cw + CW_PAD;                    // N*64 f32 = 25.6 MB
    u32*   KV = (u32*)(Q + (size_t)N_PTS * 64); // N*64 u32 = 25.6 MB

    qkv_mfma_kernel<<<625, 256, 0, stream>>>(
        x,
        d_in[3],  d_in[4],  d_in[5],  d_in[6],  d_in[7],  d_in[8],
        d_in[9],  d_in[10], d_in[11], d_in[12], d_in[13], d_in[14],
        d_in[15], d_in[16], d_in[17], d_in[18], d_in[19], d_in[20],
        d_in[21], d_in[22], cw, Q, KV);                    // 625*10*16 = 100000
    attn_kernel<<<N_PTS / 8, 256, 0, stream>>>(p, idx, x, cw, Q, KV, d_out);
}

// Round 16
// 336.334 us; speedup vs baseline: 2.1085x; 2.1085x over previous
//
#include <hip/hip_runtime.h>
#include <hip/hip_bf16.h>

typedef unsigned int u32;
typedef unsigned short u16;
typedef __attribute__((ext_vector_type(8))) short short8;   // 8 bf16 (4 VGPRs)
typedef __attribute__((ext_vector_type(4))) short short4v;  // 4 u16 (8B LDS read)
typedef __attribute__((ext_vector_type(4))) float f32x4;    // MFMA C/D
typedef __attribute__((ext_vector_type(2))) float f32x2;    // v_pk_fma_f32 operand
typedef __attribute__((ext_vector_type(4))) u32 u32x4;

#define N_PTS 100000
#define NSAMP 16

__device__ __forceinline__ float lo2f(u32 u){ return __uint_as_float(u << 16); }
__device__ __forceinline__ float hi2f(u32 u){ return __uint_as_float(u & 0xffff0000u); }
__device__ __forceinline__ float us2f(u16 u){ return __uint_as_float(((u32)u) << 16); }

// round-to-nearest-even f32 -> bf16 bits (finite values only)
__device__ __forceinline__ u16 f2bf(float f) {
    u32 u = __float_as_uint(f);
    return (u16)((u + 0x7fffu + ((u >> 16) & 1u)) >> 16);
}
__device__ __forceinline__ u32 pack2(float k, float v) {
    return (u32)f2bf(k) | ((u32)f2bf(v) << 16);
}

// wave-local LDS RAW fence. The "memory" clobber ALSO pins global loads
// above it (they cannot sink past) — R4/R11-proven mechanism that keeps
// the whole gather burst issued up-front.
#define WAVE_LDS_FENCE() asm volatile("s_waitcnt lgkmcnt(0)" ::: "memory")

// Runtime input-dtype probe (must be called by ALL threads of the block).
__device__ __forceinline__ bool detect_f32(const u16* __restrict__ xprobe) {
    float f = us2f(xprobe[(threadIdx.x & 63) * 2]);
    int cnt = __syncthreads_count(fabsf(f) > 1024.0f ? 1 : 0);
    return cnt >= 8;
}

// generic raw-weight element load (fp32 or bf16 source)
__device__ __forceinline__ float rawf(const void* s, int i, bool isf32) {
    return isf32 ? ((const float*)s)[i] : us2f(((const u16*)s)[i]);
}

// canonical fp32 weight-block offsets (floats) — written by qkv block 0,
// consumed by attn (stream-ordered).
#define OFF_WP1  0
#define OFF_BP1  12
#define OFF_GP   16
#define OFF_BP   20
#define OFF_WP2  24
#define OFF_BP2  216
#define OFF_G1   280
#define OFF_BB1  344
#define OFF_BA   408
#define OFF_G2   416
#define OFF_BB2  424
#define OFF_BW   432
#define OFF_WAT  448     /* WaT[s][c] : 8 x 64 f32 (transposed Wa) */
#define OFF_WBT  960     /* WbT[t][s] : 8 x 8  f32 (transposed Wb) */
#define CW_PAD   4096    /* pad to 16 KB of floats */

// ---------------------------------------------------------------------------
// K1: MFMA QKV projection + (block 0) attn-weight canonicalization.
// (round-13 version: swapped operands + vectorized float4/uint4 epilogue —
// passing & frozen.)
// ---------------------------------------------------------------------------
#define QKV_TPB 10
__global__ __launch_bounds__(256) void qkv_mfma_kernel(
    const u16* __restrict__ xraw,
    const void* s0,  const void* s1,  const void* s2,  const void* s3,
    const void* s4,  const void* s5,  const void* s6,  const void* s7,
    const void* s8,  const void* s9,  const void* s10, const void* s11,
    const void* s12, const void* s13, const void* s14, const void* s15,
    const void* s16, const void* s17, const void* s18, const void* s19,
    float* __restrict__ cw,
    float* __restrict__ Q, u32* __restrict__ KV)
{
    bool isf32 = detect_f32(xraw);
    const int w   = threadIdx.x >> 6;
    const int l   = threadIdx.x & 63;
    const int col = l & 15;
    const int g   = l >> 4;

    // ---- block 0: write attn's canonical weight block ----
    if (blockIdx.x == 0) {
        const void* srcs[12] = {s6,s7,s8,s9,s10,s11,s12,s13,s15,s16,s17,s19};
        const int   sizes[12]= {9,3,3,3,192,64,64,64,8,8,8,8};
        const int   offs[12] = {OFF_WP1,OFF_BP1,OFF_GP,OFF_BP,OFF_WP2,OFF_BP2,
                                OFF_G1,OFF_BB1,OFF_BA,OFF_G2,OFF_BB2,OFF_BW};
        int tid = threadIdx.x;
        for (int a = 0; a < 12; a++)
            for (int k = tid; k < sizes[a]; k += 256)
                cw[offs[a] + k] = rawf(srcs[a], k, isf32);
        // WaT[s][c] = Wa[c][s] ; WbT[t][s] = Wb[s][t]
        for (int t = tid; t < 512 + 64; t += 256) {
            if (t < 512) {
                int s = t >> 6, cc = t & 63;
                cw[OFF_WAT + s * 64 + cc] = rawf(s14, cc * 8 + s, isf32);
            } else {
                int r = t - 512;
                int tt = r >> 3, ss = r & 7;
                cw[OFF_WBT + tt * 8 + ss] = rawf(s18, ss * 8 + tt, isf32);
            }
        }
    }

    // ---- build W fragments in registers: hi/lo bf16 planes ----
    const void* wsrc[3] = {s0, s2, s4};
    short8 bh[3][2], bl[3][2];
#pragma unroll
    for (int m = 0; m < 3; m++)
#pragma unroll
        for (int kh = 0; kh < 2; kh++)
#pragma unroll
            for (int j = 0; j < 8; j++) {
                float wv_ = rawf(wsrc[m], (kh * 32 + g * 8 + j) * 64 + w * 16 + col, isf32);
                u16 hb = f2bf(wv_);
                bh[m][kh][j] = (short)hb;
                bl[m][kh][j] = (short)f2bf(wv_ - us2f(hb));
            }
    // per-reg bias (D row m = g*4+r -> weight col w*16+g*4+r), loop-invariant
    float bq[4], bk[4], bv[4];
#pragma unroll
    for (int r = 0; r < 4; r++) {
        bq[r] = rawf(s1, w * 16 + g * 4 + r, isf32);
        bk[r] = rawf(s3, w * 16 + g * 4 + r, isf32);
        bv[r] = rawf(s5, w * 16 + g * 4 + r, isf32);
    }

#define LOAD_A(IT, AH, AL)                                                        \
    {                                                                             \
        const int M0_ = (blockIdx.x * QKV_TPB + (IT)) * 16;                       \
        if (isf32) {                                                              \
            const float4* xf = (const float4*)xraw;                               \
            _Pragma("unroll")                                                     \
            for (int kh = 0; kh < 2; kh++) {                                      \
                float4 f0 = xf[(size_t)(M0_ + col) * 16 + kh * 8 + g * 2];        \
                float4 f1 = xf[(size_t)(M0_ + col) * 16 + kh * 8 + g * 2 + 1];    \
                float ff[8] = {f0.x, f0.y, f0.z, f0.w, f1.x, f1.y, f1.z, f1.w};   \
                _Pragma("unroll")                                                 \
                for (int j = 0; j < 8; j++) {                                     \
                    u16 hb_ = f2bf(ff[j]);                                        \
                    AH[kh][j] = (short)hb_;                                       \
                    AL[kh][j] = (short)f2bf(ff[j] - us2f(hb_));                   \
                }                                                                 \
            }                                                                     \
        } else {                                                                  \
            const short8* xb = (const short8*)xraw;                               \
            _Pragma("unroll")                                                     \
            for (int kh = 0; kh < 2; kh++)                                        \
                AH[kh] = xb[(size_t)(M0_ + col) * 8 + kh * 4 + g];                \
        }                                                                         \
    }

    short8 ahA[2], alA[2], ahB[2], alB[2];
    LOAD_A(0, ahA, alA);

#pragma unroll
    for (int it = 0; it < QKV_TPB; it++) {
        short8 (&ah)[2] = (it & 1) ? ahB : ahA;
        short8 (&al)[2] = (it & 1) ? alB : alA;
        short8 (&ahN)[2] = (it & 1) ? ahA : ahB;
        short8 (&alN)[2] = (it & 1) ? alA : alB;
        if (it + 1 < QKV_TPB) LOAD_A(it + 1, ahN, alN);

        const int M0 = (blockIdx.x * QKV_TPB + it) * 16;
        f32x4 aQ = {bq[0], bq[1], bq[2], bq[3]};
        f32x4 aK = {bk[0], bk[1], bk[2], bk[3]};
        f32x4 aV = {bv[0], bv[1], bv[2], bv[3]};

        // SWAPPED operand order: D = Wfrag . xfrag  -> D[m=W col][n=x row]
#pragma unroll
        for (int kh = 0; kh < 2; kh++) {
            aQ = __builtin_amdgcn_mfma_f32_16x16x32_bf16(bh[0][kh], ah[kh], aQ, 0, 0, 0);
            aK = __builtin_amdgcn_mfma_f32_16x16x32_bf16(bh[1][kh], ah[kh], aK, 0, 0, 0);
            aV = __builtin_amdgcn_mfma_f32_16x16x32_bf16(bh[2][kh], ah[kh], aV, 0, 0, 0);
            aQ = __builtin_amdgcn_mfma_f32_16x16x32_bf16(bl[0][kh], ah[kh], aQ, 0, 0, 0);
            aK = __builtin_amdgcn_mfma_f32_16x16x32_bf16(bl[1][kh], ah[kh], aK, 0, 0, 0);
            aV = __builtin_amdgcn_mfma_f32_16x16x32_bf16(bl[2][kh], ah[kh], aV, 0, 0, 0);
            if (isf32) {
                aQ = __builtin_amdgcn_mfma_f32_16x16x32_bf16(bh[0][kh], al[kh], aQ, 0, 0, 0);
                aK = __builtin_amdgcn_mfma_f32_16x16x32_bf16(bh[1][kh], al[kh], aK, 0, 0, 0);
                aV = __builtin_amdgcn_mfma_f32_16x16x32_bf16(bh[2][kh], al[kh], aV, 0, 0, 0);
            }
        }

        // ---- vectorized epilogue: lane owns row M0+(l&15), cols w*16+g*4.. ----
        {
            const int row = M0 + col;                 // col == l&15
            float4 qv = {aQ[0], aQ[1], aQ[2], aQ[3]};
            *(float4*)&Q[(size_t)row * 64 + w * 16 + g * 4] = qv;
            u32x4 kvv = {pack2(aK[0], aV[0]), pack2(aK[1], aV[1]),
                         pack2(aK[2], aV[2]), pack2(aK[3], aV[3])};
            *(u32x4*)&KV[(size_t)row * 64 + w * 16 + g * 4] = kvv;
        }
    }
#undef LOAD_A
}

// ---------------------------------------------------------------------------
// K2: fused attention — round 16 = round 14 STRUCTURE (proven no-spill,
// VGPR 64) with wvbuf stored as bf16 (u16). LDS 38.9 -> 21.5 KB:
//   wvbufh[8][16*68] u16 (st1->st2; first 512B of each slice reused as w2
//                         f32 overlay in st4->st5)
//   tbbuf [8][16*8] f32  (st2->st3; [0..63] reused as hbuf pre-st1)
// __launch_bounds__(256,6) -> 6 blocks/CU = 24 waves/CU (R14: 16).
// NOT the R15 phased structure (that provoked compiler spill: WRITE_SIZE
// 25MB -> 1.5GB). Spill tripwire: WRITE_SIZE must stay 25000.
// ---------------------------------------------------------------------------
__global__ __launch_bounds__(256, 6) void attn_kernel(
    const u16* __restrict__ P, const int* __restrict__ IDX,
    const u16* __restrict__ xprobe, const float* __restrict__ cw,
    const float* __restrict__ Q, const u32* __restrict__ KV,
    void* __restrict__ OUT)
{
    __shared__ __align__(16) u16   wvbufh[8][NSAMP * 68]; // bf16 relu(bn1(w))
    __shared__ __align__(16) float tbbuf[8][NSAMP * 8];   // f32; hbuf overlay

    bool isf32 = detect_f32(xprobe);

    const int pt  = threadIdx.x >> 6;
    const int c   = threadIdx.x & 63;
    const int i0  = blockIdx.x * 8 + pt * 2;   // grid*8 == N_PTS exactly
    const int i1  = i0 + 1;
    const int sl0 = pt * 2, sl1 = sl0 + 1;     // wave-owned LDS slices
    const float rs = 1.0f / sqrtf(1.0f + 1e-5f);

    // lifetime-overlay views (all wave-owned slices)
    float* hb0 = &tbbuf[sl0][0];          // hbuf pt0 (64 floats, dead after st1)
    float* hb1 = &tbbuf[sl1][0];          // hbuf pt1
    float* w20 = (float*)&wvbufh[sl0][0]; // softmax weights pt0 (128 f32, 512B)
    float* w21 = (float*)&wvbufh[sl1][0]; // softmax weights pt1

    // ---- burst: indices + 32 KV gathers + Q + P, all before the fence ----
    const int jv0 = IDX[(size_t)i0 * NSAMP + (c & 15)];
    const int jv1 = IDX[(size_t)i1 * NSAMP + (c & 15)];

    u32 kv0[NSAMP], kv1[NSAMP];
    const u32* KVc = KV + c;
#pragma unroll
    for (int n = 0; n < NSAMP; n++) {
        int j = __builtin_amdgcn_readlane(jv0, n);   // SGPR -> SALU addressing
        kv0[n] = KVc[(size_t)j << 6];
    }
#pragma unroll
    for (int n = 0; n < NSAMP; n++) {
        int j = __builtin_amdgcn_readlane(jv1, n);
        kv1[n] = KVc[(size_t)j << 6];
    }

    const float qq0 = Q[(size_t)i0 * 64 + c];
    const float qq1 = Q[(size_t)i1 * 64 + c];

    // ---- distributed h-MLP for both points: lane (n,d) = (c/3, c%3) ----
    const float* Pf = (const float*)P;
    const int n_p  = c / 3;
    const int d_p  = c - n_p * 3;
    const int np15 = n_p & 15;
    const int jp0  = __shfl(jv0, np15, 64);
    const int jp1  = __shfl(jv1, np15, 64);
    float pj0, pj1, pid0, pid1;
    if (isf32) {
        pj0 = Pf[(size_t)jp0 * 3 + d_p];  pid0 = Pf[(size_t)i0 * 3 + d_p];
        pj1 = Pf[(size_t)jp1 * 3 + d_p];  pid1 = Pf[(size_t)i1 * 3 + d_p];
    } else {
        pj0 = us2f(P[(size_t)jp0 * 3 + d_p]);  pid0 = us2f(P[(size_t)i0 * 3 + d_p]);
        pj1 = us2f(P[(size_t)jp1 * 3 + d_p]);  pid1 = us2f(P[(size_t)i1 * 3 + d_p]);
    }
    const float pr0 = pj0 - pid0, pr1 = pj1 - pid1;
    const int lb = np15 * 3;
    const float pA0 = __shfl(pr0, lb + 0, 64);
    const float pA1 = __shfl(pr0, lb + 1, 64);
    const float pA2 = __shfl(pr0, lb + 2, 64);
    const float pB0 = __shfl(pr1, lb + 0, 64);
    const float pB1 = __shfl(pr1, lb + 1, 64);
    const float pB2 = __shfl(pr1, lb + 2, 64);
    {
        float gd  = cw[OFF_GP + d_p] * rs;
        float w0s = cw[OFF_WP1 + 0 * 3 + d_p] * gd;
        float w1s = cw[OFF_WP1 + 1 * 3 + d_p] * gd;
        float w2s = cw[OFF_WP1 + 2 * 3 + d_p] * gd;
        float bs  = cw[OFF_BP1 + d_p] * gd + cw[OFF_BP + d_p];
        float hA = fmaxf(fmaf(pA2, w2s, fmaf(pA1, w1s, fmaf(pA0, w0s, bs))), 0.0f);
        float hB = fmaxf(fmaf(pB2, w2s, fmaf(pB1, w1s, fmaf(pB0, w0s, bs))), 0.0f);
        if (c < 48) {
            hb0[np15 * 4 + d_p] = hA;
            hb1[np15 * 4 + d_p] = hB;
        }
    }
    WAVE_LDS_FENCE();   // hbuf RAW (same wave) + pins the 32 gathers above

    // per-lane channel constants (L1-hot)
    const float wp2c0 = cw[OFF_WP2 + 0 * 64 + c];
    const float wp2c1 = cw[OFF_WP2 + 1 * 64 + c];
    const float wp2c2 = cw[OFF_WP2 + 2 * 64 + c];
    const float bp2c  = cw[OFF_BP2 + c];
    const float g1c   = cw[OFF_G1  + c] * rs;
    const float bb1c  = cw[OFF_BB1 + c];

    float pv0[NSAMP], pv1[NSAMP];

    // ---- stage 1 (both points): relation input into LDS (bf16) ----
#pragma unroll
    for (int n = 0; n < NSAMP; n++) {
        float4 hb = *((const float4*)&hb0[n * 4]);
        float pe = fmaf(hb.z, wp2c2, fmaf(hb.y, wp2c1, fmaf(hb.x, wp2c0, bp2c)));
        float kk = lo2f(kv0[n]);
        float vv = hi2f(kv0[n]);
        wvbufh[sl0][n * 68 + c] = f2bf(fmaxf(fmaf(kk - qq0 + pe, g1c, bb1c), 0.0f));
        pv0[n] = vv + pe;
    }
#pragma unroll
    for (int n = 0; n < NSAMP; n++) {
        float4 hb = *((const float4*)&hb1[n * 4]);
        float pe = fmaf(hb.z, wp2c2, fmaf(hb.y, wp2c1, fmaf(hb.x, wp2c0, bp2c)));
        float kk = lo2f(kv1[n]);
        float vv = hi2f(kv1[n]);
        wvbufh[sl1][n * 68 + c] = f2bf(fmaxf(fmaf(kk - qq1 + pe, g1c, bb1c), 0.0f));
        pv1[n] = vv + pe;
    }
    __syncthreads();

    // ---- stage 2 (both points, merged reps): bf16 LDS reads, f32 acc ----
    const int s2s = c & 7, s2n = c >> 3;
    f32x2 aA0 = {cw[OFF_BA + s2s], 0.0f};
    f32x2 aA1 = aA0, aB0 = aA0, aB1 = aA0;
    const float4* waT4 = (const float4*)(cw + OFF_WAT + s2s * 64);
#pragma unroll
    for (int c4 = 0; c4 < 16; c4++) {
        float4 wa = waT4[c4];
        f32x2 waA = {wa.x, wa.y}, waB = {wa.z, wa.w};
        short4v hA0 = *((const short4v*)&wvbufh[sl0][s2n * 68 + c4 * 4]);
        short4v hA1 = *((const short4v*)&wvbufh[sl0][(s2n + 8) * 68 + c4 * 4]);
        short4v hB0 = *((const short4v*)&wvbufh[sl1][s2n * 68 + c4 * 4]);
        short4v hB1 = *((const short4v*)&wvbufh[sl1][(s2n + 8) * 68 + c4 * 4]);
        f32x2 tA0a = {us2f((u16)hA0.x), us2f((u16)hA0.y)};
        f32x2 tA0b = {us2f((u16)hA0.z), us2f((u16)hA0.w)};
        f32x2 tA1a = {us2f((u16)hA1.x), us2f((u16)hA1.y)};
        f32x2 tA1b = {us2f((u16)hA1.z), us2f((u16)hA1.w)};
        f32x2 tB0a = {us2f((u16)hB0.x), us2f((u16)hB0.y)};
        f32x2 tB0b = {us2f((u16)hB0.z), us2f((u16)hB0.w)};
        f32x2 tB1a = {us2f((u16)hB1.x), us2f((u16)hB1.y)};
        f32x2 tB1b = {us2f((u16)hB1.z), us2f((u16)hB1.w)};
        aA0 += tA0a * waA;  aA0 += tA0b * waB;
        aA1 += tA1a * waA;  aA1 += tA1b * waB;
        aB0 += tB0a * waA;  aB0 += tB0b * waB;
        aB1 += tB1a * waA;  aB1 += tB1b * waB;
    }
    {
        float g2s = cw[OFF_G2 + s2s] * rs, bb2s = cw[OFF_BB2 + s2s];
        tbbuf[sl0][s2n * 8 + s2s]       = fmaxf(fmaf(aA0.x + aA0.y, g2s, bb2s), 0.0f);
        tbbuf[sl0][(s2n + 8) * 8 + s2s] = fmaxf(fmaf(aA1.x + aA1.y, g2s, bb2s), 0.0f);
        tbbuf[sl1][s2n * 8 + s2s]       = fmaxf(fmaf(aB0.x + aB0.y, g2s, bb2s), 0.0f);
        tbbuf[sl1][(s2n + 8) * 8 + s2s] = fmaxf(fmaf(aB1.x + aB1.y, g2s, bb2s), 0.0f);
    }
    __syncthreads();

    // ---- stage 3 (both points): logits in registers ----
    f32x2 wA0 = {cw[OFF_BW + s2s], 0.0f};
    f32x2 wA1 = wA0, wB0 = wA0, wB1 = wA0;
    {
        float4 wb0 = *(const float4*)(cw + OFF_WBT + s2s * 8);
        float4 wb1 = *(const float4*)(cw + OFF_WBT + s2s * 8 + 4);
        f32x2 b0 = {wb0.x, wb0.y}, b1 = {wb0.z, wb0.w};
        f32x2 b2 = {wb1.x, wb1.y}, b3 = {wb1.z, wb1.w};
#define ACC_LOGIT(ACC, SL, ROW)                                                   \
        {                                                                         \
            float4 t0_ = *((const float4*)&tbbuf[SL][(ROW) * 8]);                 \
            float4 t1_ = *((const float4*)&tbbuf[SL][(ROW) * 8 + 4]);             \
            f32x2 u0_ = {t0_.x, t0_.y}, u1_ = {t0_.z, t0_.w};                     \
            f32x2 u2_ = {t1_.x, t1_.y}, u3_ = {t1_.z, t1_.w};                     \
            ACC += u0_ * b0;  ACC += u1_ * b1;  ACC += u2_ * b2;  ACC += u3_ * b3;\
        }
        ACC_LOGIT(wA0, sl0, s2n)
        ACC_LOGIT(wA1, sl0, s2n + 8)
        ACC_LOGIT(wB0, sl1, s2n)
        ACC_LOGIT(wB1, sl1, s2n + 8)
#undef ACC_LOGIT
    }
    float lA0 = wA0.x + wA0.y, lA1 = wA1.x + wA1.y;
    float lB0 = wB0.x + wB0.y, lB1 = wB1.x + wB1.y;

    // ---- stage 4: softmax per point; weights into w2 overlay (f32) ----
    {
        float m0 = fmaxf(lA0, lA1);
        m0 = fmaxf(m0, __shfl_xor(m0, 8, 64));
        m0 = fmaxf(m0, __shfl_xor(m0, 16, 64));
        m0 = fmaxf(m0, __shfl_xor(m0, 32, 64));
        float e00 = __expf(lA0 - m0), e01 = __expf(lA1 - m0);
        float s0 = e00 + e01;
        s0 += __shfl_xor(s0, 8, 64);
        s0 += __shfl_xor(s0, 16, 64);
        s0 += __shfl_xor(s0, 32, 64);
        float inv0 = 1.0f / s0;
        w20[s2n * 8 + s2s]       = e00 * inv0;
        w20[(s2n + 8) * 8 + s2s] = e01 * inv0;

        float m1 = fmaxf(lB0, lB1);
        m1 = fmaxf(m1, __shfl_xor(m1, 8, 64));
        m1 = fmaxf(m1, __shfl_xor(m1, 16, 64));
        m1 = fmaxf(m1, __shfl_xor(m1, 32, 64));
        float e10 = __expf(lB0 - m1), e11 = __expf(lB1 - m1);
        float s1 = e10 + e11;
        s1 += __shfl_xor(s1, 8, 64);
        s1 += __shfl_xor(s1, 16, 64);
        s1 += __shfl_xor(s1, 32, 64);
        float inv1 = 1.0f / s1;
        w21[s2n * 8 + s2s]       = e10 * inv1;
        w21[(s2n + 8) * 8 + s2s] = e11 * inv1;
    }
    __syncthreads();

    // ---- stage 5 (both points): out[c] = sum_n pv[n] * w[n][c&7] ----
    f32x2 ov0 = {0.0f, 0.0f}, ov1 = {0.0f, 0.0f};
#pragma unroll
    for (int n = 0; n < NSAMP; n += 2) {
        f32x2 p0 = {pv0[n], pv0[n + 1]};
        f32x2 w0 = {w20[n * 8 + s2s], w20[(n + 1) * 8 + s2s]};
        f32x2 p1 = {pv1[n], pv1[n + 1]};
        f32x2 w1 = {w21[n * 8 + s2s], w21[(n + 1) * 8 + s2s]};
        ov0 += p0 * w0;
        ov1 += p1 * w1;
    }
    float o0 = ov0.x + ov0.y;
    float o1 = ov1.x + ov1.y;
    if (isf32) {
        ((float*)OUT)[(size_t)i0 * 64 + c] = o0;
        ((float*)OUT)[(size_t)i1 * 64 + c] = o1;
    } else {
        ((__hip_bfloat16*)OUT)[(size_t)i0 * 64 + c] = __float2bfloat16(o0);
        ((__hip_bfloat16*)OUT)[(size_t)i1 * 64 + c] = __float2bfloat16(o1);
    }
}

// ---------------------------------------------------------------------------
extern "C" void kernel_launch(void* const* d_in, const int* in_sizes, int n_in,
                              void* d_out, int out_size, void* d_ws, size_t ws_size,
                              hipStream_t stream)
{
    const u16* p   = (const u16*)d_in[0];
    const u16* x   = (const u16*)d_in[1];
    const int* idx = (const int*)d_in[2];

    // workspace layout: cw 16KB + Q 25.6MB + KV 25.6MB ≈ 51.2 MB
    float* cw = (float*)d_ws;                   // 16 KB
    float* Q  = cw + CW_PAD;                    // N*64 f32 = 25.6 MB
    u32*   KV = (u32*)(Q + (size_t)N_PTS * 64); // N*64 u32 = 25.6 MB

    qkv_mfma_kernel<<<625, 256, 0, stream>>>(
        x,
        d_in[3],  d_in[4],  d_in[5],  d_in[6],  d_in[7],  d_in[8],
        d_in[9],  d_in[10], d_in[11], d_in[12], d_in[13], d_in[14],
        d_in[15], d_in[16], d_in[17], d_in[18], d_in[19], d_in[20],
        d_in[21], d_in[22], cw, Q, KV);                    // 625*10*16 = 100000
    attn_kernel<<<N_PTS / 8, 256, 0, stream>>>(p, idx, x, cw, Q, KV, d_out);
}